// Round 8
// baseline (16.577 us; speedup 1.0000x reference)
//
#include <hip/hip_runtime.h>
#include <math.h>

#define NC 5
#define NBASIS (NC + 1)
#define EPSF 1e-10f
#define BIGF 1e10f

typedef float v4f __attribute__((ext_vector_type(4)));

struct BMat { float b[2 * NC][NBASIS]; };

// Reproduce numpy.linalg.svd(L)'s null-space basis (rows nC-1.. of Vt).
// LAPACK dgesdd (M=4 << N=10) LQ path: basis col c = H1 H2 H3 H4 e_{M+c}.
static BMat compute_basis() {
    const int m = NC - 1;      // 4
    const int n = 2 * NC;      // 10
    double A[NC - 1][2 * NC];
    for (int r = 0; r < m; ++r)
        for (int c = 0; c < n; ++c) A[r][c] = 0.0;
    for (int k = 1; k < NC; ++k) {
        double xk = (double)k / (double)NC;
        int i = k - 1;
        A[i][2 * i]     = xk;   A[i][2 * i + 1] = 1.0;
        A[i][2 * i + 2] = -xk;  A[i][2 * i + 3] = -1.0;
    }
    double tau[NC - 1];
    for (int i = 0; i < m; ++i) {
        double alpha = A[i][i];
        double xs = 0.0;
        for (int j = i + 1; j < n; ++j) xs += A[i][j] * A[i][j];
        double xnorm = sqrt(xs);
        if (xnorm == 0.0) { tau[i] = 0.0; continue; }
        double beta = (alpha >= 0.0 ? -1.0 : 1.0) * sqrt(alpha * alpha + xs);
        tau[i] = (beta - alpha) / beta;
        double inv = 1.0 / (alpha - beta);
        for (int j = i + 1; j < n; ++j) A[i][j] *= inv;
        A[i][i] = beta;
        for (int r = i + 1; r < m; ++r) {
            double dot = A[r][i];
            for (int j = i + 1; j < n; ++j) dot += A[r][j] * A[i][j];
            dot *= tau[i];
            A[r][i] -= dot;
            for (int j = i + 1; j < n; ++j) A[r][j] -= dot * A[i][j];
        }
    }
    BMat B;
    for (int c = 0; c < NBASIS; ++c) {
        double v[2 * NC];
        for (int r = 0; r < n; ++r) v[r] = 0.0;
        v[m + c] = 1.0;
        for (int i = m - 1; i >= 0; --i) {
            double dot = v[i];
            for (int j = i + 1; j < n; ++j) dot += A[i][j] * v[j];
            dot *= tau[i];
            v[i] -= dot;
            for (int j = i + 1; j < n; ++j) v[j] -= dot * A[i][j];
        }
        for (int r = 0; r < n; ++r) B.b[r][c] = (float)v[r];
    }
    return B;
}

// Per-cell closed-form eval. For start cell c with slope a (ae = a or 1e-7
// epsilon-model if |a|<=EPS), y0 = -b/ae, L = log|y-y0|:
//   log|v| = log|ae| + L, so t_hit = (log|v_bndry| - log|v|)/a = K'dir - L*rcp
// with K'dir = (log|ve_bndry| - log|ae|)*rcp, pre-set to BIG when the
// reference would mark the crossing invalid (at_edge or ratio<=0).
// Outcomes (verified equivalent to the 6-iter reference loop, rounds 2-7):
//   no-cross (t_hit>=1): z = y + (y-y0)*expm1(ae), lj = a
//   stuck (v<0 crossing, t_hit<1): ref re-enters cell at left knot with
//     ratio==1 -> t_hit=0 forever => z = kL_c, lj = a*t_hit
//   cross (v>=0, t_hit<1): walk full-cell traverse times tR (prefix F),
//     stop cell j = min{j>=c+1 : F[j+1] >= 1 - t_hit + F[c+1]} (cap 4),
//     TT = 1 - t_hit - (F[j]-F[c+1]),
//     z = kL_j + Q_j*expm1(ae_j*TT), lj = a*t_hit + (G[j]-G[c+1]) + ae_j*TT
// Tables are 5-entry x 16B => ds_read_b128 gathers are bank-conflict-free.
__global__ __launch_bounds__(256) void cpab_fused(
    const float* __restrict__ x, const float* __restrict__ theta,
    const float* __restrict__ pa, const float* __restrict__ pb,
    const float* __restrict__ pc, const float* __restrict__ pd,
    float* __restrict__ out, int N, BMat Bm)
{
#pragma clang fp contract(off)
    __shared__ float sA[2 * NC];
    __shared__ float sa[NC], sb[NC], stR[NC], sljR[NC];
    __shared__ float4 sC1[NC];   // {y0, rcp, K'1, K'2}
    __shared__ float4 sC2[NC];   // {em1ae, a, F[c+1], G[c+1]}
    __shared__ float4 sC3[NC];   // {Q, ae, F[c], G[c]}   (indexed by stop cell j)
    __shared__ float sFu[3];     // F[2], F[3], F[4] (wave-uniform)
    __shared__ float sAff[4];
    int tid = threadIdx.x;

    // ---- issue global loads first: latency hides under the table build ----
    int nv = N >> 2;
    int base = blockIdx.x * 512 + tid;      // block tile: 512 float4s
    bool ok0 = base < nv;
    bool ok1 = (base + 256) < nv;
    float4 xv0, xv1;
    const float4* x4 = (const float4*)x;
    if (ok0) xv0 = x4[base];
    if (ok1) xv1 = x4[base + 256];

    // ---- phase 1: A = B*theta, affine scalars ----
    if (tid < 2 * NC) {
        float acc = 0.0f;
#pragma unroll
        for (int j = 0; j < NBASIS; ++j) acc += Bm.b[tid][j] * theta[j];
        sA[tid] = acc;
    }
    if (tid == 2 * NC) {
        sAff[0] = pa[0]; sAff[1] = pb[0]; sAff[2] = pc[0]; sAff[3] = pd[0];
    }
    __syncthreads();

    // ---- phase 2: per-cell traverse times (bit-identical to reference) ----
    if (tid < NC) {
        int m = tid;
        float a = sA[2 * m], b = sA[2 * m + 1];
        float kL = (float)m / 5.0f, kR = (float)(m + 1) / 5.0f;
        float vL = a * kL + b, vR = a * kR + b;
        bool vok = fabsf(vL) > EPSF;
        float vs = vok ? vL : 1.0f;
        float ratio = vR / vs;
        bool aok = fabsf(a) > EPSF;
        float as = aok ? a : 1.0f;
        float t = aok ? (logf(ratio > EPSF ? ratio : 1.0f) / as)
                      : ((kR - kL) / vs);
        bool valid = vok && (ratio > EPSF) && (m != NC - 1) && (vL >= 0.0f);
        sa[m] = a; sb[m] = b;
        stR[m]  = valid ? t : BIGF;
        sljR[m] = valid ? (a * t) : 0.0f;
    }
    __syncthreads();

    // ---- phase 3: per-cell eval tables (each lane recomputes prefix) ----
    if (tid < NC) {
        int c = tid;
        float a = sa[c], b = sb[c];
        bool aok = fabsf(a) > EPSF;
        float ae  = aok ? a : 1e-7f;          // epsilon-slope model
        float rcp = 1.0f / ae;
        float y0  = -b * rcp;
        float La  = logf(fabsf(ae));
        float kLx = (float)c / 5.0f, kRx = (float)(c + 1) / 5.0f;
        float veL = ae * kLx + b;
        float veR = ae * kRx + b;
        // K' = BIG when reference marks crossing invalid (edge / ratio<=0)
        float KP1 = (c == NC - 1 || veR <= 0.0f)
                    ? BIGF : (logf(fabsf(veR)) - La) * rcp;
        float KP2 = (c == 0 || veL >= 0.0f)
                    ? BIGF : (logf(fabsf(veL)) - La) * rcp;
        // prefix sums; clamp tR at 2 (any tR>=1 already blocks the walk, and
        // clamping keeps F in a precision-safe range for the comparisons)
        float F[NC + 1], G[NC + 1];
        F[0] = 0.0f; G[0] = 0.0f;
#pragma unroll
        for (int m = 0; m < NC; ++m) {
            F[m + 1] = F[m] + fminf(stR[m], 2.0f);
            G[m + 1] = G[m] + ((stR[m] < 2.0f) ? sljR[m] : 0.0f);
        }
        sC1[c] = make_float4(y0, rcp, KP1, KP2);
        sC2[c] = make_float4(expm1f(ae), a, F[c + 1], G[c + 1]);
        sC3[c] = make_float4(veL * rcp, ae, F[c], G[c]);
        if (c == 0) { sFu[0] = F[2]; sFu[1] = F[3]; sFu[2] = F[4]; }
    }
    __syncthreads();

    // ---- streaming eval ----
    float affa = sAff[0], affb = sAff[1], affc = sAff[2], affd = sAff[3];
    float ljadd = logf(affa * affc);   // exactly 0 for identity affine
    float vF2 = sFu[0], vF3 = sFu[1], vF4 = sFu[2];
    v4f* oz = (v4f*)out;
    v4f* ol = (v4f*)(out + N);

    float xin[8];
    xin[0] = xv0.x; xin[1] = xv0.y; xin[2] = xv0.z; xin[3] = xv0.w;
    xin[4] = xv1.x; xin[5] = xv1.y; xin[6] = xv1.z; xin[7] = xv1.w;
    float zi[8], li[8];
#pragma unroll
    for (int q = 0; q < 8; ++q) {
        float y = affa * xin[q] + affb;        // mul+add order matches ref
        int c = (int)floorf(y * 5.0f);
        c = c < 0 ? 0 : (c > 4 ? 4 : c);
        float4 C1 = sC1[c];
        float4 C2 = sC2[c];
        float d = y - C1.x;                    // y - y0
        float L = __logf(fmaxf(fabsf(d), 1e-37f));
        float Lr = L * C1.y;                   // L * rcp
        bool pos = (d >= 0.0f) == (C1.y > 0.0f);   // sign(v)=sign(ae)*sign(d)
        float t = (pos ? C1.z : C1.w) - Lr;    // t_hit (BIG-folded if invalid)
        bool cross = (t < 1.0f);
        float ts = cross ? t : 1.0f;
        float lj_c = C2.y * ts;                // a * t_step (stuck & no-cross)
        float znc = fmaf(d, C2.x, y);          // no-cross: y + d*expm1(ae)
        // cross: find stop cell j via wave-uniform prefix compares
        float R = 1.0f - t + C2.z;             // 1 - t_hit + F[c+1]
        int j = c + 1;
        j += (c <= 0 && vF2 < R) ? 1 : 0;
        j += (c <= 1 && vF3 < R) ? 1 : 0;
        j += (c <= 2 && vF4 < R) ? 1 : 0;
        j = j > 4 ? 4 : j;                     // guard predicated-off lanes
        float4 C3 = sC3[j];
        float TT = 1.0f - t - (C3.z - C2.z);   // 1 - t - (F[j]-F[c+1])
        float arg = C3.y * TT;                 // ae_j * TT
        float E = __expf(arg) - 1.0f;          // expm1 w/ small-arg poly
        float pm = arg * (1.0f + arg * (0.5f + arg * 0.16666667f));
        if (fabsf(arg) < 0.03f) E = pm;
        float zc  = fmaf(C3.x, E, (float)j * 0.2f);   // kL_j + Q_j*E
        float ljx = lj_c + (C3.w - C2.w) + arg;       // + (G[j]-G[c+1]) + aj*TT
        float z  = cross ? (pos ? zc : (float)c * 0.2f) : znc;
        float lj = (cross && pos) ? ljx : lj_c;
        zi[q] = fmaf(affc, z, affd);
        li[q] = lj + ljadd;
    }
    if (ok0) {
        v4f z0 = {zi[0], zi[1], zi[2], zi[3]};
        v4f l0 = {li[0], li[1], li[2], li[3]};
        __builtin_nontemporal_store(z0, &oz[base]);
        __builtin_nontemporal_store(l0, &ol[base]);
    }
    if (ok1) {
        v4f z1 = {zi[4], zi[5], zi[6], zi[7]};
        v4f l1 = {li[4], li[5], li[6], li[7]};
        __builtin_nontemporal_store(z1, &oz[base + 256]);
        __builtin_nontemporal_store(l1, &ol[base + 256]);
    }
}

extern "C" void kernel_launch(void* const* d_in, const int* in_sizes, int n_in,
                              void* d_out, int out_size, void* d_ws, size_t ws_size,
                              hipStream_t stream) {
    const float* x     = (const float*)d_in[0];
    const float* theta = (const float*)d_in[1];
    const float* pa    = (const float*)d_in[2];
    const float* pb    = (const float*)d_in[3];
    const float* pc    = (const float*)d_in[4];
    const float* pd    = (const float*)d_in[5];
    float* out = (float*)d_out;
    int N = in_sizes[0];

    BMat Bm = compute_basis();

    int nv = N >> 2;                 // 1,048,576 float4s
    int grid = (nv + 511) / 512;     // 2048 blocks: 8/CU, one residency gen
    cpab_fused<<<grid, 256, 0, stream>>>(x, theta, pa, pb, pc, pd, out, N, Bm);
}